// Round 2
// baseline (1087.456 us; speedup 1.0000x reference)
//
#include <hip/hip_runtime.h>

// ---------------------------------------------------------------------------
// MonarchMixerLayer, fp32. B=32, N=D=1024, s=32.
// Two kernels:
//   p1: per (b, 16-wide d-tile): monarch(m1) -> relu(nk*.) -> monarch(m2) -> x_tilde
//   p2: per (b, 16-row n-tile):  monarch(m3) -> relu(dk*.) -> monarch(m4) -> +resid -> LN
// Tile: 1024 x 16 floats = 64 KB dynamic LDS (within default 64KB limit; the
// 128KB round-0 variant risked launch failure).
// Swizzled layout: addr(n,l) = n*16 + (l ^ 2*((n>>2)&7))  -- pair-preserving,
// conflict-free (or 2-way == free) for every access phase incl. the LN pass.
//
// Monarch math (derived from reference):
//   OUT[a][b] = sum_j R[b][a][j] * T[j][b],  T[j][b] = sum_k L[j][b][k] * V[k][j]
// Stage A (thread p): T[p][c] from column cells (k*32+p); store at cell (c*32+p).
// Stage B (thread r): OUT[a][r] from row cells (r*32+j); store at cell (a*32+r).
// ---------------------------------------------------------------------------

struct EpiNone {
  __device__ __forceinline__ void operator()(float2&, int, int) const {}
};
struct EpiReluNK {           // v *= nk[d0+l][n]; relu    (nkp = nk + d0*1024)
  const float* nkp;
  __device__ __forceinline__ void operator()(float2& v, int n, int l2) const {
    float a = v.x * nkp[((size_t)l2 << 10) + n];
    float b = v.y * nkp[((size_t)(l2 + 1) << 10) + n];
    v.x = a > 0.f ? a : 0.f;
    v.y = b > 0.f ? b : 0.f;
  }
};
struct EpiReluDK {           // v *= dk[n]; relu
  const float* dk;
  __device__ __forceinline__ void operator()(float2& v, int n, int) const {
    float w = dk[n];
    float a = v.x * w, b = v.y * w;
    v.x = a > 0.f ? a : 0.f;
    v.y = b > 0.f ? b : 0.f;
  }
};
struct EpiResid {            // v += x_tilde[row l][n]    (xtp = xt + (b*1024+n0)*1024)
  const float* xtp;
  __device__ __forceinline__ void operator()(float2& v, int n, int l2) const {
    v.x += xtp[((size_t)l2 << 10) + n];
    v.y += xtp[((size_t)(l2 + 1) << 10) + n];
  }
};

// One full monarch over the 16 resident vectors. Entry: tile valid, all synced.
// Exit: tile holds OUT (epilogue applied), all synced.
template <class Epi>
__device__ __forceinline__ void monarch16(float* tile,
                                          const float* __restrict__ L,
                                          const float* __restrict__ R,
                                          int tid, const Epi& epi) {
  // ---- Stage A: thread (g2=2g, p, r0) computes T[p][r0..r0+15] for 2 vectors.
  {
    const int g2 = (tid & 7) << 1;
    const int p = (tid >> 3) & 31;
    const int r0 = (tid >> 8) << 4;
    const int CA = (p << 4) + (g2 ^ (((p >> 2) & 7) << 1));  // swz const: n=?*32+p
    float2 X[32];
#pragma unroll
    for (int j = 0; j < 32; ++j)
      X[j] = *(const float2*)&tile[(j << 9) + CA];
    __syncthreads();  // all reads done before any in-place write
    const float* Wp = L + (p << 10) + (r0 << 5);
#pragma unroll
    for (int i = 0; i < 16; ++i) {
      const float4* w4 = (const float4*)(Wp + (i << 5));
      float ax = 0.f, ay = 0.f;
#pragma unroll
      for (int q = 0; q < 8; ++q) {
        float4 w = w4[q];
        ax = fmaf(w.x, X[4 * q + 0].x, ax); ay = fmaf(w.x, X[4 * q + 0].y, ay);
        ax = fmaf(w.y, X[4 * q + 1].x, ax); ay = fmaf(w.y, X[4 * q + 1].y, ay);
        ax = fmaf(w.z, X[4 * q + 2].x, ax); ay = fmaf(w.z, X[4 * q + 2].y, ay);
        ax = fmaf(w.w, X[4 * q + 3].x, ax); ay = fmaf(w.w, X[4 * q + 3].y, ay);
      }
      float2 o; o.x = ax; o.y = ay;
      *(float2*)&tile[((r0 + i) << 9) + CA] = o;  // cell ( (r0+i)*32+p , 2g )
    }
  }
  __syncthreads();
  // ---- Stage B: thread (g2, r, u0) computes OUT[u0..u0+15][r] for 2 vectors.
  {
    const int g2 = (tid & 7) << 1;
    const int r = (tid >> 3) & 31;
    const int u0 = (tid >> 8) << 4;
    float2 M[32];
    {
      const int rbase = r << 9;
#pragma unroll
      for (int p = 0; p < 32; ++p)
        M[p] = *(const float2*)&tile[rbase + (p << 4) + (g2 ^ (((p >> 2) & 7) << 1))];
    }
    __syncthreads();  // all row reads done before cross-thread writes
    const float* Wr = R + (r << 10) + (u0 << 5);
    const int CB = (r << 4) + (g2 ^ (((r >> 2) & 7) << 1));  // swz const: n=?*32+r
#pragma unroll
    for (int i = 0; i < 16; ++i) {
      const float4* w4 = (const float4*)(Wr + (i << 5));
      float ax = 0.f, ay = 0.f;
#pragma unroll
      for (int q = 0; q < 8; ++q) {
        float4 w = w4[q];
        ax = fmaf(w.x, M[4 * q + 0].x, ax); ay = fmaf(w.x, M[4 * q + 0].y, ay);
        ax = fmaf(w.y, M[4 * q + 1].x, ax); ay = fmaf(w.y, M[4 * q + 1].y, ay);
        ax = fmaf(w.z, M[4 * q + 2].x, ax); ay = fmaf(w.z, M[4 * q + 2].y, ay);
        ax = fmaf(w.w, M[4 * q + 3].x, ax); ay = fmaf(w.w, M[4 * q + 3].y, ay);
      }
      float2 o; o.x = ax; o.y = ay;
      const int n = ((u0 + i) << 5) + r;
      epi(o, n, g2);
      *(float2*)&tile[((u0 + i) << 9) + CB] = o;  // cell ( (u0+i)*32+r , 2g )
    }
  }
  __syncthreads();
}

// Phase 1: sequence mixing. grid (64 d-tiles, 32 b), block 512, 64KB LDS.
__global__ __launch_bounds__(512, 4) void p1_kernel(
    const float* __restrict__ x, const float* __restrict__ m1L,
    const float* __restrict__ m1R, const float* __restrict__ m2L,
    const float* __restrict__ m2R, const float* __restrict__ nk,
    float* __restrict__ xt_out) {
  extern __shared__ float tile[];
  const int b = blockIdx.y, d0 = blockIdx.x << 4;
  const int tid = (int)threadIdx.x;
  const float* xb = x + ((size_t)b << 20);
  {  // load x[b, n, d0+0..15]: float4 global -> two swizzled b64 LDS writes
    const int gq = tid & 3, qq = tid >> 2;             // qq in 0..127
    const int A = (gq << 2) ^ (((qq >> 2) & 7) << 1);  // t(n) = (qq>>2)&7
#pragma unroll
    for (int j = 0; j < 8; ++j) {
      const int n = (j << 7) + qq;
      float4 v = *(const float4*)&xb[((size_t)n << 10) + d0 + (gq << 2)];
      float2 lo; lo.x = v.x; lo.y = v.y;
      float2 hi; hi.x = v.z; hi.y = v.w;
      *(float2*)&tile[(n << 4) + A] = lo;        // elems e=0,1
      *(float2*)&tile[(n << 4) + (A ^ 2)] = hi;  // elems e=2,3
    }
  }
  __syncthreads();
  EpiReluNK e1; e1.nkp = nk + ((size_t)d0 << 10);
  monarch16(tile, m1L, m1R, tid, e1);
  EpiNone e0;
  monarch16(tile, m2L, m2R, tid, e0);
  {  // store x_tilde[b, n, d0+0..15]
    const int gq = tid & 3, qq = tid >> 2;
    const int A = (gq << 2) ^ (((qq >> 2) & 7) << 1);
    float* ob = xt_out + ((size_t)b << 20);
#pragma unroll
    for (int j = 0; j < 8; ++j) {
      const int n = (j << 7) + qq;
      float2 lo = *(const float2*)&tile[(n << 4) + A];
      float2 hi = *(const float2*)&tile[(n << 4) + (A ^ 2)];
      float4 v; v.x = lo.x; v.y = lo.y; v.z = hi.x; v.w = hi.y;
      *(float4*)&ob[((size_t)n << 10) + d0 + (gq << 2)] = v;
    }
  }
}

// Phase 2: dim mixing + residual + LN. grid (64 n-tiles, 32 b). In-place on d_out
// (block-exclusive rows; all reads precede the final store).
__global__ __launch_bounds__(512, 4) void p2_kernel(
    const float* xt, const float* __restrict__ m3L,
    const float* __restrict__ m3R, const float* __restrict__ m4L,
    const float* __restrict__ m4R, const float* __restrict__ dk,
    const float* __restrict__ gamma, const float* __restrict__ beta,
    float* out) {
  extern __shared__ float tile[];
  const int b = blockIdx.y, n0 = blockIdx.x << 4;
  const int tid = (int)threadIdx.x;
  const float* xtp = xt + ((((size_t)b << 10) + n0) << 10);
  {  // load 16 rows: float4 along d from one row -> 4 swizzled b32 LDS writes
    const int l = tid & 15, qq = tid >> 4;  // qq in 0..31
    const float* xr = xtp + ((size_t)l << 10);
    const int C3 = l ^ ((qq & 7) << 1);  // t(d+e) = qq&7
#pragma unroll
    for (int j = 0; j < 8; ++j) {
      const int d = (j << 7) + (qq << 2);
      float4 v = *(const float4*)&xr[d];
      tile[((d + 0) << 4) + C3] = v.x;
      tile[((d + 1) << 4) + C3] = v.y;
      tile[((d + 2) << 4) + C3] = v.z;
      tile[((d + 3) << 4) + C3] = v.w;
    }
  }
  __syncthreads();
  EpiReluDK e3; e3.dk = dk;
  monarch16(tile, m3L, m3R, tid, e3);
  EpiResid e4; e4.xtp = xtp;
  monarch16(tile, m4L, m4R, tid, e4);
  {  // LN over d per row; same-row threads = 32 consecutive tids (half-wave shfl)
    const int q = tid & 31, l = tid >> 5;
    const int base = (q << 4) + (l ^ (((q >> 2) & 7) << 1));
    float vbuf[32];
    float s = 0.f;
#pragma unroll
    for (int j = 0; j < 32; ++j) {
      vbuf[j] = tile[(j << 9) + base];  // cell (j*32+q, l)
      s += vbuf[j];
    }
#pragma unroll
    for (int m = 1; m <= 16; m <<= 1) s += __shfl_xor(s, m);
    const float mu = s * (1.f / 1024.f);
    float vs = 0.f;
#pragma unroll
    for (int j = 0; j < 32; ++j) {
      float d = vbuf[j] - mu;
      vs += d * d;
    }
#pragma unroll
    for (int m = 1; m <= 16; m <<= 1) vs += __shfl_xor(vs, m);
    const float rs = rsqrtf(vs * (1.f / 1024.f) + 1e-5f);
    float* orow = out + ((((size_t)b << 10) + n0 + l) << 10);
#pragma unroll
    for (int j = 0; j < 32; ++j) {  // row-contiguous stores: 128B/row/instr
      const int n = (j << 5) + q;
      orow[n] = (vbuf[j] - mu) * rs * gamma[n] + beta[n];
    }
  }
}

extern "C" void kernel_launch(void* const* d_in, const int* in_sizes, int n_in,
                              void* d_out, int out_size, void* d_ws, size_t ws_size,
                              hipStream_t stream) {
  (void)in_sizes; (void)n_in; (void)out_size; (void)d_ws; (void)ws_size;
  const float* x   = (const float*)d_in[0];
  const float* m1L = (const float*)d_in[1];
  const float* m1R = (const float*)d_in[2];
  const float* m2L = (const float*)d_in[3];
  const float* m2R = (const float*)d_in[4];
  const float* m3L = (const float*)d_in[5];
  const float* m3R = (const float*)d_in[6];
  const float* m4L = (const float*)d_in[7];
  const float* m4R = (const float*)d_in[8];
  const float* nk  = (const float*)d_in[9];
  const float* dk  = (const float*)d_in[10];
  const float* gam = (const float*)d_in[11];
  const float* bet = (const float*)d_in[12];
  float* out = (float*)d_out;

  dim3 grid(64, 32), block(512);
  const size_t lds = 1024 * 16 * sizeof(float);  // 64 KB exactly
  hipLaunchKernelGGL(p1_kernel, grid, block, lds, stream,
                     x, m1L, m1R, m2L, m2R, nk, out);
  hipLaunchKernelGGL(p2_kernel, grid, block, lds, stream,
                     out, m3L, m3R, m4L, m4R, dk, gam, bet, out);
}

// Round 3
// 922.553 us; speedup vs baseline: 1.1787x; 1.1787x over previous
//
#include <hip/hip_runtime.h>

// ---------------------------------------------------------------------------
// MonarchMixerLayer fp32, B=32, N=D=1024, s=32.
//   p1 (per b, 32-wide d-tile): monarch(m1) -> relu(nk*) -> monarch(m2) -> xt
//   p2 (per b, 32-row n-tile):  monarch(m3) -> relu(dk*) -> monarch(m4) -> +xt -> LN
// Tile: 1024 x 32 fp32 = 128 KB static LDS, 1024 threads, 1 block/CU.
// Layout: cell(n,l) at n*32 + (l ^ 4*t(n)), t(n) = ((n>>2)^(n>>5))&7.
//   - monarch stage accesses (float2, 16-lane groups sweep chunk): conflict-free
//   - transpose-load scalar writes: 8-way (one-time), LN reads: 4-way (cheap)
// All global loads/stores touch full 128B lines (fixes round-2's 2-3x HBM
// amplification: 719MB -> ~265MB per kernel).
// Monarch math (verified correct in round 2):
//   out[u*32+r] = sum_m R[r][u][m] * sum_k L[m][r][k] * in[k*32+m]
// ---------------------------------------------------------------------------

#define TILE_ELEMS (1024 * 32)

struct EpiNone {
  __device__ __forceinline__ void operator()(float2&, int) const {}
};
struct EpiReluDK {  // v *= dk[n]; relu  (broadcast across lanes, L1-resident)
  const float* dk;
  __device__ __forceinline__ void operator()(float2& v, int n) const {
    float w = dk[n];
    float a = v.x * w, b = v.y * w;
    v.x = a > 0.f ? a : 0.f;
    v.y = b > 0.f ? b : 0.f;
  }
};

// One monarch over the 32 resident vectors. Entry/exit: tile valid, synced.
template <class Epi>
__device__ __forceinline__ void monarch32(float* tile,
                                          const float* __restrict__ L,
                                          const float* __restrict__ R,
                                          int tid, const Epi epi) {
  const int l2 = (tid & 15) << 1;   // float2 chunk
  const int pr = (tid >> 4) & 31;   // p (stage A) / r (stage B)
  const int h  = tid >> 9;          // output half
  const int pb = pr << 5;
  const int blA = l2 ^ (((pr >> 2) & 7) << 2);  // for cells n = c*32+pr
  const int blB = l2 ^ ((pr & 7) << 2);         // for cells n = pr*32+m
  // ---- Stage A: T[pr][c] = sum_k L[pr][c][k] * V[k*32+pr]
  {
    float2 X[32];
#pragma unroll
    for (int j = 0; j < 32; ++j)
      X[j] = *(const float2*)&tile[(j << 10) + pb + (blA ^ ((j & 7) << 2))];
    __syncthreads();  // all reads done before in-place writes
    const float* Lp = L + (pr << 10) + (h << 9);
#pragma unroll
    for (int i = 0; i < 16; ++i) {
      const float4* w4 = (const float4*)(Lp + (i << 5));
      float ax = 0.f, ay = 0.f;
#pragma unroll
      for (int q = 0; q < 8; ++q) {
        float4 w = w4[q];
        ax = fmaf(w.x, X[4 * q + 0].x, ax); ay = fmaf(w.x, X[4 * q + 0].y, ay);
        ax = fmaf(w.y, X[4 * q + 1].x, ax); ay = fmaf(w.y, X[4 * q + 1].y, ay);
        ax = fmaf(w.z, X[4 * q + 2].x, ax); ay = fmaf(w.z, X[4 * q + 2].y, ay);
        ax = fmaf(w.w, X[4 * q + 3].x, ax); ay = fmaf(w.w, X[4 * q + 3].y, ay);
      }
      const int c = (h << 4) + i;
      float2 o; o.x = ax; o.y = ay;
      *(float2*)&tile[(c << 10) + pb + (blA ^ ((c & 7) << 2))] = o;
    }
  }
  __syncthreads();
  // ---- Stage B: OUT[u*32+pr] = sum_m R[pr][u][m] * T[pr*32+m]
  {
    float2 M[32];
#pragma unroll
    for (int m = 0; m < 32; ++m)
      M[m] = *(const float2*)&tile[(pr << 10) + (m << 5) + (blB ^ ((m >> 2) << 2))];
    __syncthreads();  // all row reads done before cross-thread writes
    const float* Rp = R + (pr << 10) + (h << 9);
#pragma unroll
    for (int i = 0; i < 16; ++i) {
      const float4* w4 = (const float4*)(Rp + (i << 5));
      float ax = 0.f, ay = 0.f;
#pragma unroll
      for (int q = 0; q < 8; ++q) {
        float4 w = w4[q];
        ax = fmaf(w.x, M[4 * q + 0].x, ax); ay = fmaf(w.x, M[4 * q + 0].y, ay);
        ax = fmaf(w.y, M[4 * q + 1].x, ax); ay = fmaf(w.y, M[4 * q + 1].y, ay);
        ax = fmaf(w.z, M[4 * q + 2].x, ax); ay = fmaf(w.z, M[4 * q + 2].y, ay);
        ax = fmaf(w.w, M[4 * q + 3].x, ax); ay = fmaf(w.w, M[4 * q + 3].y, ay);
      }
      const int u = (h << 4) + i;
      const int n = (u << 5) + pr;
      float2 o; o.x = ax; o.y = ay;
      epi(o, n);
      *(float2*)&tile[(u << 10) + pb + (blA ^ ((u & 7) << 2))] = o;
    }
  }
  __syncthreads();
}

// Phase 1: sequence mixing. grid (32 d-tiles, 32 b), block 1024.
__global__ __launch_bounds__(1024, 4) void p1_kernel(
    const float* __restrict__ x, const float* __restrict__ m1L,
    const float* __restrict__ m1R, const float* __restrict__ m2L,
    const float* __restrict__ m2R, const float* __restrict__ nk,
    float* __restrict__ xt_out) {
  __shared__ float tile[TILE_ELEMS];
  const int b = blockIdx.y, d0 = blockIdx.x << 5;
  const int tid = (int)threadIdx.x;
  {  // load x[b, n, d0..d0+31]: 8 rows x 128B full lines per wave-instr
    const int g4 = tid & 7, nn = tid >> 3, l4 = g4 << 2;
    const float* xb = x + ((size_t)b << 20) + d0 + l4;
#pragma unroll
    for (int j = 0; j < 8; ++j) {
      const int n = (j << 7) + nn;
      float4 v = *(const float4*)&xb[(size_t)n << 10];
      const int t = ((n >> 2) ^ (n >> 5)) & 7;
      *(float4*)&tile[(n << 5) + (l4 ^ (t << 2))] = v;
    }
  }
  __syncthreads();
  monarch32(tile, m1L, m1R, tid, EpiNone());
  {  // relu(nk[d0+l][n] * v): n-fast mapping -> nk reads 128B/half-wave
    const int q = tid & 31, l = tid >> 5;
    const int bl = l ^ (((q >> 2) & 7) << 2);
    const float* nkr = nk + ((size_t)(d0 + l) << 10);
#pragma unroll
    for (int j = 0; j < 32; ++j) {
      const int n = (j << 5) + q;
      const int a = (j << 10) + (q << 5) + (bl ^ ((j & 7) << 2));
      float v = tile[a] * nkr[n];
      tile[a] = v > 0.f ? v : 0.f;  // own cells only -> no barrier inside
    }
  }
  __syncthreads();
  monarch32(tile, m2L, m2R, tid, EpiNone());
  {  // store x_tilde: full 128B lines
    const int g4 = tid & 7, nn = tid >> 3, l4 = g4 << 2;
    float* ob = xt_out + ((size_t)b << 20) + d0 + l4;
#pragma unroll
    for (int j = 0; j < 8; ++j) {
      const int n = (j << 7) + nn;
      const int t = ((n >> 2) ^ (n >> 5)) & 7;
      float4 v = *(const float4*)&tile[(n << 5) + (l4 ^ (t << 2))];
      *(float4*)&ob[(size_t)n << 10] = v;
    }
  }
}

// Phase 2: dim mixing + residual + LN. grid (32 n-tiles, 32 b). In-place on
// d_out (block-exclusive rows; per-thread read-before-write in LN phase).
__global__ __launch_bounds__(1024, 4) void p2_kernel(
    const float* xt, const float* __restrict__ m3L,
    const float* __restrict__ m3R, const float* __restrict__ m4L,
    const float* __restrict__ m4R, const float* __restrict__ dk,
    const float* __restrict__ gamma, const float* __restrict__ beta,
    float* out) {
  __shared__ float tile[TILE_ELEMS];
  const int b = blockIdx.y, n0 = blockIdx.x << 5;
  const int tid = (int)threadIdx.x;
  const float* xrows = xt + ((((size_t)b << 10) + n0) << 10);
  {  // transpose-load 32 rows: global 1KB contiguous/wave-instr; LDS 8-way (one-time)
    const int c = tid & 255, lg = tid >> 8;
    const int t = (c ^ (c >> 3)) & 7;
#pragma unroll
    for (int k = 0; k < 8; ++k) {
      const int l = (lg << 3) + k;
      float4 v = *(const float4*)&xrows[((size_t)l << 10) + (c << 2)];
      const int lx = l ^ (t << 2);
      tile[(c << 7) + lx] = v.x;
      tile[(c << 7) + 32 + lx] = v.y;
      tile[(c << 7) + 64 + lx] = v.z;
      tile[(c << 7) + 96 + lx] = v.w;
    }
  }
  __syncthreads();
  EpiReluDK e3; e3.dk = dk;
  monarch32(tile, m3L, m3R, tid, e3);
  monarch32(tile, m4L, m4R, tid, EpiNone());
  {  // h = y + xt (resid re-read, 128B/half-wave); two-pass LN; coalesced store
    const int q = tid & 31, l = tid >> 5;
    const int bl = l ^ (((q >> 2) & 7) << 2);
    const float* xr = xrows + ((size_t)l << 10);
    float hbuf[32];
    float s = 0.f;
#pragma unroll
    for (int j = 0; j < 32; ++j) {
      const int n = (j << 5) + q;
      float hv = tile[(j << 10) + (q << 5) + (bl ^ ((j & 7) << 2))] + xr[n];
      hbuf[j] = hv;
      s += hv;
    }
#pragma unroll
    for (int m = 1; m <= 16; m <<= 1) s += __shfl_xor(s, m);
    const float mu = s * (1.f / 1024.f);
    float vs = 0.f;
#pragma unroll
    for (int j = 0; j < 32; ++j) {
      float d = hbuf[j] - mu;
      vs = fmaf(d, d, vs);
    }
#pragma unroll
    for (int m = 1; m <= 16; m <<= 1) vs += __shfl_xor(vs, m);
    const float rs = rsqrtf(vs * (1.f / 1024.f) + 1e-5f);
    float* orow = out + ((((size_t)b << 10) + n0 + l) << 10);
#pragma unroll
    for (int j = 0; j < 32; ++j) {
      const int n = (j << 5) + q;
      orow[n] = (hbuf[j] - mu) * rs * gamma[n] + beta[n];
    }
  }
}

extern "C" void kernel_launch(void* const* d_in, const int* in_sizes, int n_in,
                              void* d_out, int out_size, void* d_ws, size_t ws_size,
                              hipStream_t stream) {
  (void)in_sizes; (void)n_in; (void)out_size; (void)d_ws; (void)ws_size;
  const float* x   = (const float*)d_in[0];
  const float* m1L = (const float*)d_in[1];
  const float* m1R = (const float*)d_in[2];
  const float* m2L = (const float*)d_in[3];
  const float* m2R = (const float*)d_in[4];
  const float* m3L = (const float*)d_in[5];
  const float* m3R = (const float*)d_in[6];
  const float* m4L = (const float*)d_in[7];
  const float* m4R = (const float*)d_in[8];
  const float* nk  = (const float*)d_in[9];
  const float* dk  = (const float*)d_in[10];
  const float* gam = (const float*)d_in[11];
  const float* bet = (const float*)d_in[12];
  float* out = (float*)d_out;

  dim3 grid(32, 32), block(1024);
  hipLaunchKernelGGL(p1_kernel, grid, block, 0, stream,
                     x, m1L, m1R, m2L, m2R, nk, out);
  hipLaunchKernelGGL(p2_kernel, grid, block, 0, stream,
                     out, m3L, m3R, m4L, m4R, dk, gam, bet, out);
}